// Round 14
// baseline (85.716 us; speedup 1.0000x reference)
//
#include <hip/hip_runtime.h>
#include <math.h>

#define D 64
#define EPS 1e-6f
#define SLOPE 0.2f

typedef _Float16 f16;
typedef _Float16 f16x4 __attribute__((ext_vector_type(4)));
typedef _Float16 f16x8 __attribute__((ext_vector_type(8)));
typedef float f32x4 __attribute__((ext_vector_type(4)));

__device__ __forceinline__ float red4(float v) {
  v += __shfl_xor(v, 16, 64);
  v += __shfl_xor(v, 32, 64);
  return v;
}
__device__ __forceinline__ float leaky(float l) {
  return (l > 0.f) ? l : SLOPE * l;
}
__device__ __forceinline__ float bperm_f(int byte_addr, float v) {
  return __int_as_float(
      __builtin_amdgcn_ds_bpermute(byte_addr, __float_as_int(v)));
}
__device__ __forceinline__ int bperm_i(int byte_addr, int v) {
  return __builtin_amdgcn_ds_bpermute(byte_addr, v);
}

// ---------------------------------------------------------------------------
// prep_kernel: fused W-transform (fragment-major f16, see R5) + CSR rowptr
// (one E-grid dispatch instead of two).
// ---------------------------------------------------------------------------
__global__ void prep_kernel(const float* __restrict__ Ww,
                            const float* __restrict__ W1w,
                            const float* __restrict__ W2w,
                            f16* __restrict__ wt,
                            const int* __restrict__ erow,
                            int* __restrict__ row_ptr, int E, int N)
{
  int e = blockIdx.x * blockDim.x + threadIdx.x;

  if (e < 3 * 4096) {
    int mat = e >> 12, idx = e & 4095;
    int n = idx >> 6, k = idx & 63;
    const float* src = (mat == 0) ? Ww : (mat == 1) ? W1w : W2w;
    int t = n >> 4, mloc = n & 15;
    int c = k >> 4, grp = (k >> 2) & 3, j = k & 3;
    int frag = mat * 16 + t * 4 + c;
    int lane = grp * 16 + mloc;
    wt[(frag << 8) + (lane << 2) + j] = (f16)src[k * 64 + n];
  }

  if (e >= E) return;
  int r = erow[e];
  if (e == 0) {
    for (int rr = 0; rr <= r; ++rr) row_ptr[rr] = 0;
  } else {
    int rp = erow[e - 1];
    for (int rr = rp + 1; rr <= r; ++rr) row_ptr[rr] = e;
  }
  if (e == E - 1) {
    for (int rr = r + 1; rr <= N; ++rr) row_ptr[rr] = E;
  }
}

// ---------------------------------------------------------------------------
// Node kernel: weights in VGPRs, grid-stride 16-node tiles.  R14: 3-buffer
// rotating prefetch (2-3 tiles = 16-24KB per wave in flight through every
// process phase) at 512 blocks — deepening per-wave ILP, NOT adding waves
// (R10 showed the 48-fragment preload must amortize over few long waves).
// ---------------------------------------------------------------------------
__global__ __launch_bounds__(256, 2) void node_kernel(
    const float* __restrict__ query, const float* __restrict__ input_,
    const f16* __restrict__ wt,
    const float* __restrict__ Wb,  const float* __restrict__ W1b,
    const float* __restrict__ W2b,
    const float* __restrict__ g1,  const float* __restrict__ b1,
    f16* __restrict__ dense_h, float* __restrict__ s1, float* __restrict__ s2,
    int N)
{
  const int lane = threadIdx.x & 63;
  const int grp  = lane >> 4;
  const int mloc = lane & 15;
  const int wave  = blockIdx.x * (blockDim.x >> 6) + (threadIdx.x >> 6);
  const int nwav  = gridDim.x * (blockDim.x >> 6);
  const int TILES = (N + 15) >> 4;

  f16x4 wd[4][4], w1r[4][4], w2r[4][4];
#pragma unroll
  for (int t = 0; t < 4; ++t)
#pragma unroll
    for (int c = 0; c < 4; ++c) {
      int f = t * 4 + c;
      wd[t][c]  = *(const f16x4*)(wt + ((f)      << 8) + (lane << 2));
      w1r[t][c] = *(const f16x4*)(wt + ((16 + f) << 8) + (lane << 2));
      w2r[t][c] = *(const f16x4*)(wt + ((32 + f) << 8) + (lane << 2));
    }
  f32x4 gk[4], bk[4];
#pragma unroll
  for (int c = 0; c < 4; ++c) {
    gk[c] = *(const f32x4*)(g1 + c * 16 + grp * 4);
    bk[c] = *(const f32x4*)(b1 + c * 16 + grp * 4);
  }
  float wbr[4];
#pragma unroll
  for (int t = 0; t < 4; ++t) wbr[t] = Wb[t * 16 + mloc];

  auto prefetch = [&](f32x4* QB, f32x4* IB, int tl) {
    int m = tl * 16 + mloc;
    bool v = (tl < TILES) && (m < N);
    size_t b = (size_t)m * D;
#pragma unroll
    for (int c = 0; c < 4; ++c) {
      int k0 = c * 16 + grp * 4;
      if (v) {
        QB[c] = *(const f32x4*)(query + b + k0);
        IB[c] = *(const f32x4*)(input_ + b + k0);
      } else {
        QB[c] = (f32x4){0.f, 0.f, 0.f, 0.f};
        IB[c] = (f32x4){0.f, 0.f, 0.f, 0.f};
      }
    }
  };

  auto process = [&](f32x4* QB, f32x4* IB, int tl) {
    float s = 0.f;
#pragma unroll
    for (int c = 0; c < 4; ++c)
#pragma unroll
      for (int j = 0; j < 4; ++j) s += IB[c][j];
    s = red4(s);
    float mu = s * (1.f / D);
    float v2 = 0.f;
#pragma unroll
    for (int c = 0; c < 4; ++c)
#pragma unroll
      for (int j = 0; j < 4; ++j) {
        float d = IB[c][j] - mu;
        v2 += d * d;
      }
    v2 = red4(v2);
    float rs = rsqrtf(v2 * (1.f / D) + EPS);

    f16x4 xh[4], qh[4];
#pragma unroll
    for (int c = 0; c < 4; ++c)
#pragma unroll
      for (int j = 0; j < 4; ++j) {
        xh[c][j] = (f16)((IB[c][j] - mu) * rs * gk[c][j] + bk[c][j]);
        qh[c][j] = (f16)QB[c][j];
      }

    const int m  = tl * 16 + mloc;
    const bool mv = (m < N);

    // dense = X @ Ww + Wb -> f16 (scalar stores: 4x32B segments/instr)
#pragma unroll
    for (int t = 0; t < 4; ++t) {
      f32x4 acc = {0.f, 0.f, 0.f, 0.f};
#pragma unroll
      for (int c = 0; c < 4; ++c)
        acc = __builtin_amdgcn_mfma_f32_16x16x16f16(xh[c], wd[t][c], acc, 0, 0, 0);
#pragma unroll
      for (int r = 0; r < 4; ++r) {
        int row = tl * 16 + grp * 4 + r;
        if (row < N)
          dense_h[(size_t)row * D + t * 16 + mloc] = (f16)(acc[r] + wbr[t]);
      }
    }

    // scores: C-row index == fragment-k index -> lane-local dots
    float dot1 = 0.f, dot2 = 0.f;
#pragma unroll
    for (int t = 0; t < 4; ++t) {
      f32x4 a1 = {0.f, 0.f, 0.f, 0.f}, a2 = {0.f, 0.f, 0.f, 0.f};
#pragma unroll
      for (int c = 0; c < 4; ++c) {
        a1 = __builtin_amdgcn_mfma_f32_16x16x16f16(w1r[t][c], qh[c], a1, 0, 0, 0);
        a2 = __builtin_amdgcn_mfma_f32_16x16x16f16(w2r[t][c], xh[c], a2, 0, 0, 0);
      }
      f32x4 b1v = *(const f32x4*)(W1b + t * 16 + grp * 4);
      f32x4 b2v = *(const f32x4*)(W2b + t * 16 + grp * 4);
#pragma unroll
      for (int r = 0; r < 4; ++r) {
        dot1 += (a1[r] + b1v[r]) * (float)qh[t][r];
        dot2 += (a2[r] + b2v[r]) * (float)xh[t][r];
      }
    }
    dot1 = red4(dot1);
    dot2 = red4(dot2);
    if (grp == 0 && mv) {
      s1[m] = tanhf(dot1);
      s2[m] = tanhf(dot2);
    }
  };

  // ---- 3-buffer rotating pipeline: 2-3 tile loads in flight at all times ----
  f32x4 q0[4], i0[4], q1[4], i1[4], q2[4], i2[4];
  int tl = wave;
  prefetch(q0, i0, tl);
  prefetch(q1, i1, tl + nwav);
  prefetch(q2, i2, tl + 2 * nwav);
  while (true) {
    if (tl >= TILES) break;
    process(q0, i0, tl);
    prefetch(q0, i0, tl + 3 * nwav);
    tl += nwav;
    if (tl >= TILES) break;
    process(q1, i1, tl);
    prefetch(q1, i1, tl + 3 * nwav);
    tl += nwav;
    if (tl >= TILES) break;
    process(q2, i2, tl);
    prefetch(q2, i2, tl + 3 * nwav);
    tl += nwav;
  }
}

// ---------------------------------------------------------------------------
// accum<NIT>: fully-unrolled bpermute gather/accumulate engine (R8/R10).
// ---------------------------------------------------------------------------
template <int NIT>
__device__ __forceinline__ void accum(const f16* __restrict__ dense_h,
                                      int eg, int fl, int c, float w,
                                      float* A)
{
#pragma unroll
  for (int it = 0; it < NIT; ++it) {
    int a = (((eg & 4) << 3) + (it << 2) + (eg & 3)) << 2;
    float wb = bperm_f(a, w);
    int   cb = bperm_i(a, c);
    f16x8 v = *(const f16x8*)(dense_h + (size_t)cb * D + (fl << 3));
#pragma unroll
    for (int j = 0; j < 8; ++j)
      A[j] = fmaf((float)v[j], wb, A[j]);
  }
}

// ---------------------------------------------------------------------------
// Edge kernel v6 (R10/R13-measured 43-44us — unchanged; 5 structural
// variants all land 43-45, consistent with a scattered-access memory plateau).
// ---------------------------------------------------------------------------
__global__ __launch_bounds__(256) void edge_kernel(
    const int* __restrict__ row_ptr, const int* __restrict__ ecol,
    const float* __restrict__ s1v, const float* __restrict__ s2v,
    const f16* __restrict__ dense_h,
    const float* __restrict__ g2, const float* __restrict__ b2,
    float* __restrict__ out, int N, int npairs)
{
  const int lane = threadIdx.x & 63;
  const int eg   = lane >> 3;
  const int fl   = lane & 7;
  const bool hi  = (lane >= 32);
  const int  sl  = lane & 31;
  const int wv0  = blockIdx.x * (blockDim.x >> 6) + (threadIdx.x >> 6);
  const int nwav = gridDim.x * (blockDim.x >> 6);

  const f32x4 gv0 = *(const f32x4*)(g2 + (fl << 3));
  const f32x4 gv1 = *(const f32x4*)(g2 + (fl << 3) + 4);
  const f32x4 bv0 = *(const f32x4*)(b2 + (fl << 3));
  const f32x4 bv1 = *(const f32x4*)(b2 + (fl << 3) + 4);

  auto prologue = [&](int pv, int& c, float& w, int& d0, int& d1,
                      int& pa, int& pb, int& pc) {
    c = 0; w = 0.f; d0 = 0; d1 = 0; pa = 0; pb = 0; pc = 0;
    if (pv >= npairs) return;
    int r0 = pv << 1;
    pa = row_ptr[r0];
    pb = row_ptr[r0 + 1];
    pc = row_ptr[min(r0 + 2, N)];
    d0 = pb - pa;
    d1 = (r0 + 1 < N) ? (pc - pb) : 0;
    int dgx = hi ? d1 : d0;
    int bse = hi ? pb : pa;
    float s1x = s1v[min(r0 + (hi ? 1 : 0), N - 1)];
    if (sl < dgx) {
      c = ecol[bse + sl];
      w = __expf(leaky(s1x + s2v[c]));
    }
  };

  auto process = [&](int pv, int c, float w, int d0, int d1,
                     int pa, int pb, int pc) {
    if (pv >= npairs) return;
    const int r0 = pv << 1;
    const int r1 = r0 + 1;
    float A[8] = {0.f, 0.f, 0.f, 0.f, 0.f, 0.f, 0.f, 0.f};
    const int maxd = max(d0, d1);

    if (maxd <= 32) {
      const int nit = (maxd + 3) >> 2;
      if      (nit <= 2) accum<2>(dense_h, eg, fl, c, w, A);
      else if (nit <= 4) accum<4>(dense_h, eg, fl, c, w, A);
      else if (nit <= 6) accum<6>(dense_h, eg, fl, c, w, A);
      else               accum<8>(dense_h, eg, fl, c, w, A);
    } else {
      float A0[8] = {0.f, 0.f, 0.f, 0.f, 0.f, 0.f, 0.f, 0.f};
      float A1[8] = {0.f, 0.f, 0.f, 0.f, 0.f, 0.f, 0.f, 0.f};
      auto rowacc = [&](int st, int en, float s1i, float* Ar) {
        for (int b = st; b < en; b += 64) {
          int nb = min(64, en - b);
          int cc = 0;
          float ww = 0.f;
          if (lane < nb) {
            cc = ecol[b + lane];
            ww = __expf(leaky(s1i + s2v[cc]));
          }
#pragma unroll
          for (int it = 0; it < 8; ++it) {
            int a = ((it << 3) + eg) << 2;
            float wb = bperm_f(a, ww);
            int   cb = bperm_i(a, cc);
            f16x8 v = *(const f16x8*)(dense_h + (size_t)cb * D + (fl << 3));
#pragma unroll
            for (int j = 0; j < 8; ++j)
              Ar[j] = fmaf((float)v[j], wb, Ar[j]);
          }
        }
      };
      rowacc(pa, pb, s1v[r0], A0);
      if (r1 < N) rowacc(pb, pc, s1v[r1], A1);
#pragma unroll
      for (int j = 0; j < 8; ++j) {
        A0[j] += __shfl_xor(A0[j], 32, 64);
        A1[j] += __shfl_xor(A1[j], 32, 64);
        A[j] = hi ? A1[j] : A0[j];
      }
    }

#pragma unroll
    for (int j = 0; j < 8; ++j) {
      A[j] += __shfl_xor(A[j], 8, 64);
      A[j] += __shfl_xor(A[j], 16, 64);
    }

    float sa = 0.f, sq = 0.f;
#pragma unroll
    for (int j = 0; j < 8; ++j) {
      sa += A[j];
      sq += A[j] * A[j];
    }
#pragma unroll
    for (int m = 4; m > 0; m >>= 1) {
      sa += __shfl_xor(sa, m, 64);
      sq += __shfl_xor(sq, m, 64);
    }
    float mu  = sa * (1.f / D);
    float var = fmaxf(sq * (1.f / D) - mu * mu, 0.f);
    float rs  = rsqrtf(var + EPS);

    f32x4 o0, o1;
#pragma unroll
    for (int j = 0; j < 4; ++j) {
      o0[j] = (A[j]     - mu) * rs * gv0[j] + bv0[j];
      o1[j] = (A[j + 4] - mu) * rs * gv1[j] + bv1[j];
    }
    if (eg == 0) {
      *(f32x4*)(out + (size_t)r0 * D + (fl << 3))     = o0;
      *(f32x4*)(out + (size_t)r0 * D + (fl << 3) + 4) = o1;
    } else if (eg == 4 && r1 < N) {
      *(f32x4*)(out + (size_t)r1 * D + (fl << 3))     = o0;
      *(f32x4*)(out + (size_t)r1 * D + (fl << 3) + 4) = o1;
    }
  };

  int cA, d0A, d1A, paA, pbA, pcA;
  int cB, d0B, d1B, paB, pbB, pcB;
  float wA, wB;

  int pv = wv0;
  prologue(pv, cA, wA, d0A, d1A, paA, pbA, pcA);
  while (pv < npairs) {
    prologue(pv + nwav, cB, wB, d0B, d1B, paB, pbB, pcB);
    process(pv, cA, wA, d0A, d1A, paA, pbA, pcA);
    pv += nwav;
    if (pv >= npairs) break;
    prologue(pv + nwav, cA, wA, d0A, d1A, paA, pbA, pcA);
    process(pv, cB, wB, d0B, d1B, paB, pbB, pcB);
    pv += nwav;
  }
}

// ---------------------------------------------------------------------------
extern "C" void kernel_launch(void* const* d_in, const int* in_sizes, int n_in,
                              void* d_out, int out_size, void* d_ws, size_t ws_size,
                              hipStream_t stream)
{
  const float* query  = (const float*)d_in[0];
  const float* input_ = (const float*)d_in[1];
  const int*   erow   = (const int*)d_in[2];
  const int*   ecol   = (const int*)d_in[3];
  const float* Ww     = (const float*)d_in[4];
  const float* Wb     = (const float*)d_in[5];
  const float* W1w    = (const float*)d_in[6];
  const float* W1b    = (const float*)d_in[7];
  const float* W2w    = (const float*)d_in[8];
  const float* W2b    = (const float*)d_in[9];
  const float* g1     = (const float*)d_in[10];
  const float* b1     = (const float*)d_in[11];
  const float* g2     = (const float*)d_in[12];
  const float* b2     = (const float*)d_in[13];

  const int N = in_sizes[0] / D;
  const int E = in_sizes[2];
  float* out = (float*)d_out;

  // ws: dense_h f16[N*D] | s1[N] | s2[N] | row_ptr[N+1] | wt f16
  char* ws = (char*)d_ws;
  f16*   dense_h = (f16*)ws;
  float* s1      = (float*)(ws + (size_t)N * D * sizeof(f16));
  float* s2      = s1 + N;
  int*   row_ptr = (int*)(s2 + N);
  uintptr_t wtp  = (uintptr_t)(row_ptr + N + 1);
  wtp = (wtp + 15) & ~(uintptr_t)15;
  f16* wt = (f16*)wtp;

  prep_kernel<<<(E + 255) / 256, 256, 0, stream>>>(Ww, W1w, W2w, wt,
                                                   erow, row_ptr, E, N);
  node_kernel<<<512, 256, 0, stream>>>(query, input_, wt, Wb, W1b,
                                       W2b, g1, b1, dense_h, s1, s2, N);
  const int npairs = (N + 1) / 2;
  edge_kernel<<<2048, 256, 0, stream>>>(row_ptr, ecol, s1, s2,
                                        dense_h, g2, b2, out, N, npairs);
}

// Round 15
// 69.223 us; speedup vs baseline: 1.2382x; 1.2382x over previous
//
#include <hip/hip_runtime.h>
#include <math.h>

#define D 64
#define EPS 1e-6f
#define SLOPE 0.2f

typedef _Float16 f16;
typedef _Float16 f16x4 __attribute__((ext_vector_type(4)));
typedef _Float16 f16x8 __attribute__((ext_vector_type(8)));
typedef float f32x4 __attribute__((ext_vector_type(4)));

__device__ __forceinline__ float red4(float v) {
  v += __shfl_xor(v, 16, 64);
  v += __shfl_xor(v, 32, 64);
  return v;
}
__device__ __forceinline__ float leaky(float l) {
  return (l > 0.f) ? l : SLOPE * l;
}
__device__ __forceinline__ float bperm_f(int byte_addr, float v) {
  return __int_as_float(
      __builtin_amdgcn_ds_bpermute(byte_addr, __float_as_int(v)));
}
__device__ __forceinline__ int bperm_i(int byte_addr, int v) {
  return __builtin_amdgcn_ds_bpermute(byte_addr, v);
}

// ---------------------------------------------------------------------------
// prep_kernel: fused W-transform (fragment-major f16, see R5) + CSR rowptr.
// ---------------------------------------------------------------------------
__global__ void prep_kernel(const float* __restrict__ Ww,
                            const float* __restrict__ W1w,
                            const float* __restrict__ W2w,
                            f16* __restrict__ wt,
                            const int* __restrict__ erow,
                            int* __restrict__ row_ptr, int E, int N)
{
  int e = blockIdx.x * blockDim.x + threadIdx.x;

  if (e < 3 * 4096) {
    int mat = e >> 12, idx = e & 4095;
    int n = idx >> 6, k = idx & 63;
    const float* src = (mat == 0) ? Ww : (mat == 1) ? W1w : W2w;
    int t = n >> 4, mloc = n & 15;
    int c = k >> 4, grp = (k >> 2) & 3, j = k & 3;
    int frag = mat * 16 + t * 4 + c;
    int lane = grp * 16 + mloc;
    wt[(frag << 8) + (lane << 2) + j] = (f16)src[k * 64 + n];
  }

  if (e >= E) return;
  int r = erow[e];
  if (e == 0) {
    for (int rr = 0; rr <= r; ++rr) row_ptr[rr] = 0;
  } else {
    int rp = erow[e - 1];
    for (int rr = rp + 1; rr <= r; ++rr) row_ptr[rr] = e;
  }
  if (e == E - 1) {
    for (int rr = r + 1; rr <= N; ++rr) row_ptr[rr] = E;
  }
}

// ---------------------------------------------------------------------------
// Node kernel — EXACT R13-measured config (~20us): weights in VGPRs,
// grid-stride 16-node tiles, 2-deep ping-pong prefetch, 512 blocks.
// (R14's 3-buffer rotation regressed to 46us: VGPR 128, occupancy 17%.)
// ---------------------------------------------------------------------------
__global__ __launch_bounds__(256, 2) void node_kernel(
    const float* __restrict__ query, const float* __restrict__ input_,
    const f16* __restrict__ wt,
    const float* __restrict__ Wb,  const float* __restrict__ W1b,
    const float* __restrict__ W2b,
    const float* __restrict__ g1,  const float* __restrict__ b1,
    f16* __restrict__ dense_h, float* __restrict__ s1, float* __restrict__ s2,
    int N)
{
  const int lane = threadIdx.x & 63;
  const int grp  = lane >> 4;
  const int mloc = lane & 15;
  const int wave  = blockIdx.x * (blockDim.x >> 6) + (threadIdx.x >> 6);
  const int nwav  = gridDim.x * (blockDim.x >> 6);
  const int TILES = (N + 15) >> 4;

  f16x4 wd[4][4], w1r[4][4], w2r[4][4];
#pragma unroll
  for (int t = 0; t < 4; ++t)
#pragma unroll
    for (int c = 0; c < 4; ++c) {
      int f = t * 4 + c;
      wd[t][c]  = *(const f16x4*)(wt + ((f)      << 8) + (lane << 2));
      w1r[t][c] = *(const f16x4*)(wt + ((16 + f) << 8) + (lane << 2));
      w2r[t][c] = *(const f16x4*)(wt + ((32 + f) << 8) + (lane << 2));
    }
  f32x4 gk[4], bk[4];
#pragma unroll
  for (int c = 0; c < 4; ++c) {
    gk[c] = *(const f32x4*)(g1 + c * 16 + grp * 4);
    bk[c] = *(const f32x4*)(b1 + c * 16 + grp * 4);
  }
  float wbr[4];
#pragma unroll
  for (int t = 0; t < 4; ++t) wbr[t] = Wb[t * 16 + mloc];

  auto prefetch = [&](f32x4* QB, f32x4* IB, int tl) {
    int m = tl * 16 + mloc;
    bool v = (tl < TILES) && (m < N);
    size_t b = (size_t)m * D;
#pragma unroll
    for (int c = 0; c < 4; ++c) {
      int k0 = c * 16 + grp * 4;
      if (v) {
        QB[c] = *(const f32x4*)(query + b + k0);
        IB[c] = *(const f32x4*)(input_ + b + k0);
      } else {
        QB[c] = (f32x4){0.f, 0.f, 0.f, 0.f};
        IB[c] = (f32x4){0.f, 0.f, 0.f, 0.f};
      }
    }
  };

  auto process = [&](f32x4* QB, f32x4* IB, int tl) {
    float s = 0.f;
#pragma unroll
    for (int c = 0; c < 4; ++c)
#pragma unroll
      for (int j = 0; j < 4; ++j) s += IB[c][j];
    s = red4(s);
    float mu = s * (1.f / D);
    float v2 = 0.f;
#pragma unroll
    for (int c = 0; c < 4; ++c)
#pragma unroll
      for (int j = 0; j < 4; ++j) {
        float d = IB[c][j] - mu;
        v2 += d * d;
      }
    v2 = red4(v2);
    float rs = rsqrtf(v2 * (1.f / D) + EPS);

    f16x4 xh[4], qh[4];
#pragma unroll
    for (int c = 0; c < 4; ++c)
#pragma unroll
      for (int j = 0; j < 4; ++j) {
        xh[c][j] = (f16)((IB[c][j] - mu) * rs * gk[c][j] + bk[c][j]);
        qh[c][j] = (f16)QB[c][j];
      }

    const int m  = tl * 16 + mloc;
    const bool mv = (m < N);

    // dense = X @ Ww + Wb -> f16 (scalar stores: 4x32B segments/instr)
#pragma unroll
    for (int t = 0; t < 4; ++t) {
      f32x4 acc = {0.f, 0.f, 0.f, 0.f};
#pragma unroll
      for (int c = 0; c < 4; ++c)
        acc = __builtin_amdgcn_mfma_f32_16x16x16f16(xh[c], wd[t][c], acc, 0, 0, 0);
#pragma unroll
      for (int r = 0; r < 4; ++r) {
        int row = tl * 16 + grp * 4 + r;
        if (row < N)
          dense_h[(size_t)row * D + t * 16 + mloc] = (f16)(acc[r] + wbr[t]);
      }
    }

    // scores: C-row index == fragment-k index -> lane-local dots
    float dot1 = 0.f, dot2 = 0.f;
#pragma unroll
    for (int t = 0; t < 4; ++t) {
      f32x4 a1 = {0.f, 0.f, 0.f, 0.f}, a2 = {0.f, 0.f, 0.f, 0.f};
#pragma unroll
      for (int c = 0; c < 4; ++c) {
        a1 = __builtin_amdgcn_mfma_f32_16x16x16f16(w1r[t][c], qh[c], a1, 0, 0, 0);
        a2 = __builtin_amdgcn_mfma_f32_16x16x16f16(w2r[t][c], xh[c], a2, 0, 0, 0);
      }
      f32x4 b1v = *(const f32x4*)(W1b + t * 16 + grp * 4);
      f32x4 b2v = *(const f32x4*)(W2b + t * 16 + grp * 4);
#pragma unroll
      for (int r = 0; r < 4; ++r) {
        dot1 += (a1[r] + b1v[r]) * (float)qh[t][r];
        dot2 += (a2[r] + b2v[r]) * (float)xh[t][r];
      }
    }
    dot1 = red4(dot1);
    dot2 = red4(dot2);
    if (grp == 0 && mv) {
      s1[m] = tanhf(dot1);
      s2[m] = tanhf(dot2);
    }
  };

  f32x4 qA[4], iA[4], qB[4], iB[4];
  int tl = wave;
  prefetch(qA, iA, tl);
  while (tl < TILES) {
    prefetch(qB, iB, tl + nwav);
    process(qA, iA, tl);
    tl += nwav;
    if (tl >= TILES) break;
    prefetch(qA, iA, tl + nwav);
    process(qB, iB, tl);
    tl += nwav;
  }
}

// ---------------------------------------------------------------------------
// accum<NIT>: fully-unrolled bpermute gather/accumulate engine (R8/R10).
// ---------------------------------------------------------------------------
template <int NIT>
__device__ __forceinline__ void accum(const f16* __restrict__ dense_h,
                                      int eg, int fl, int c, float w,
                                      float* A)
{
#pragma unroll
  for (int it = 0; it < NIT; ++it) {
    int a = (((eg & 4) << 3) + (it << 2) + (eg & 3)) << 2;
    float wb = bperm_f(a, w);
    int   cb = bperm_i(a, c);
    f16x8 v = *(const f16x8*)(dense_h + (size_t)cb * D + (fl << 3));
#pragma unroll
    for (int j = 0; j < 8; ++j)
      A[j] = fmaf((float)v[j], wb, A[j]);
  }
}

// ---------------------------------------------------------------------------
// Edge kernel v6 (R10/R13-measured 43-44us — unchanged).
// ---------------------------------------------------------------------------
__global__ __launch_bounds__(256) void edge_kernel(
    const int* __restrict__ row_ptr, const int* __restrict__ ecol,
    const float* __restrict__ s1v, const float* __restrict__ s2v,
    const f16* __restrict__ dense_h,
    const float* __restrict__ g2, const float* __restrict__ b2,
    float* __restrict__ out, int N, int npairs)
{
  const int lane = threadIdx.x & 63;
  const int eg   = lane >> 3;
  const int fl   = lane & 7;
  const bool hi  = (lane >= 32);
  const int  sl  = lane & 31;
  const int wv0  = blockIdx.x * (blockDim.x >> 6) + (threadIdx.x >> 6);
  const int nwav = gridDim.x * (blockDim.x >> 6);

  const f32x4 gv0 = *(const f32x4*)(g2 + (fl << 3));
  const f32x4 gv1 = *(const f32x4*)(g2 + (fl << 3) + 4);
  const f32x4 bv0 = *(const f32x4*)(b2 + (fl << 3));
  const f32x4 bv1 = *(const f32x4*)(b2 + (fl << 3) + 4);

  auto prologue = [&](int pv, int& c, float& w, int& d0, int& d1,
                      int& pa, int& pb, int& pc) {
    c = 0; w = 0.f; d0 = 0; d1 = 0; pa = 0; pb = 0; pc = 0;
    if (pv >= npairs) return;
    int r0 = pv << 1;
    pa = row_ptr[r0];
    pb = row_ptr[r0 + 1];
    pc = row_ptr[min(r0 + 2, N)];
    d0 = pb - pa;
    d1 = (r0 + 1 < N) ? (pc - pb) : 0;
    int dgx = hi ? d1 : d0;
    int bse = hi ? pb : pa;
    float s1x = s1v[min(r0 + (hi ? 1 : 0), N - 1)];
    if (sl < dgx) {
      c = ecol[bse + sl];
      w = __expf(leaky(s1x + s2v[c]));
    }
  };

  auto process = [&](int pv, int c, float w, int d0, int d1,
                     int pa, int pb, int pc) {
    if (pv >= npairs) return;
    const int r0 = pv << 1;
    const int r1 = r0 + 1;
    float A[8] = {0.f, 0.f, 0.f, 0.f, 0.f, 0.f, 0.f, 0.f};
    const int maxd = max(d0, d1);

    if (maxd <= 32) {
      const int nit = (maxd + 3) >> 2;
      if      (nit <= 2) accum<2>(dense_h, eg, fl, c, w, A);
      else if (nit <= 4) accum<4>(dense_h, eg, fl, c, w, A);
      else if (nit <= 6) accum<6>(dense_h, eg, fl, c, w, A);
      else               accum<8>(dense_h, eg, fl, c, w, A);
    } else {
      float A0[8] = {0.f, 0.f, 0.f, 0.f, 0.f, 0.f, 0.f, 0.f};
      float A1[8] = {0.f, 0.f, 0.f, 0.f, 0.f, 0.f, 0.f, 0.f};
      auto rowacc = [&](int st, int en, float s1i, float* Ar) {
        for (int b = st; b < en; b += 64) {
          int nb = min(64, en - b);
          int cc = 0;
          float ww = 0.f;
          if (lane < nb) {
            cc = ecol[b + lane];
            ww = __expf(leaky(s1i + s2v[cc]));
          }
#pragma unroll
          for (int it = 0; it < 8; ++it) {
            int a = ((it << 3) + eg) << 2;
            float wb = bperm_f(a, ww);
            int   cb = bperm_i(a, cc);
            f16x8 v = *(const f16x8*)(dense_h + (size_t)cb * D + (fl << 3));
#pragma unroll
            for (int j = 0; j < 8; ++j)
              Ar[j] = fmaf((float)v[j], wb, Ar[j]);
          }
        }
      };
      rowacc(pa, pb, s1v[r0], A0);
      if (r1 < N) rowacc(pb, pc, s1v[r1], A1);
#pragma unroll
      for (int j = 0; j < 8; ++j) {
        A0[j] += __shfl_xor(A0[j], 32, 64);
        A1[j] += __shfl_xor(A1[j], 32, 64);
        A[j] = hi ? A1[j] : A0[j];
      }
    }

#pragma unroll
    for (int j = 0; j < 8; ++j) {
      A[j] += __shfl_xor(A[j], 8, 64);
      A[j] += __shfl_xor(A[j], 16, 64);
    }

    float sa = 0.f, sq = 0.f;
#pragma unroll
    for (int j = 0; j < 8; ++j) {
      sa += A[j];
      sq += A[j] * A[j];
    }
#pragma unroll
    for (int m = 4; m > 0; m >>= 1) {
      sa += __shfl_xor(sa, m, 64);
      sq += __shfl_xor(sq, m, 64);
    }
    float mu  = sa * (1.f / D);
    float var = fmaxf(sq * (1.f / D) - mu * mu, 0.f);
    float rs  = rsqrtf(var + EPS);

    f32x4 o0, o1;
#pragma unroll
    for (int j = 0; j < 4; ++j) {
      o0[j] = (A[j]     - mu) * rs * gv0[j] + bv0[j];
      o1[j] = (A[j + 4] - mu) * rs * gv1[j] + bv1[j];
    }
    if (eg == 0) {
      *(f32x4*)(out + (size_t)r0 * D + (fl << 3))     = o0;
      *(f32x4*)(out + (size_t)r0 * D + (fl << 3) + 4) = o1;
    } else if (eg == 4 && r1 < N) {
      *(f32x4*)(out + (size_t)r1 * D + (fl << 3))     = o0;
      *(f32x4*)(out + (size_t)r1 * D + (fl << 3) + 4) = o1;
    }
  };

  int cA, d0A, d1A, paA, pbA, pcA;
  int cB, d0B, d1B, paB, pbB, pcB;
  float wA, wB;

  int pv = wv0;
  prologue(pv, cA, wA, d0A, d1A, paA, pbA, pcA);
  while (pv < npairs) {
    prologue(pv + nwav, cB, wB, d0B, d1B, paB, pbB, pcB);
    process(pv, cA, wA, d0A, d1A, paA, pbA, pcA);
    pv += nwav;
    if (pv >= npairs) break;
    prologue(pv + nwav, cA, wA, d0A, d1A, paA, pbA, pcA);
    process(pv, cB, wB, d0B, d1B, paB, pbB, pcB);
    pv += nwav;
  }
}

// ---------------------------------------------------------------------------
extern "C" void kernel_launch(void* const* d_in, const int* in_sizes, int n_in,
                              void* d_out, int out_size, void* d_ws, size_t ws_size,
                              hipStream_t stream)
{
  const float* query  = (const float*)d_in[0];
  const float* input_ = (const float*)d_in[1];
  const int*   erow   = (const int*)d_in[2];
  const int*   ecol   = (const int*)d_in[3];
  const float* Ww     = (const float*)d_in[4];
  const float* Wb     = (const float*)d_in[5];
  const float* W1w    = (const float*)d_in[6];
  const float* W1b    = (const float*)d_in[7];
  const float* W2w    = (const float*)d_in[8];
  const float* W2b    = (const float*)d_in[9];
  const float* g1     = (const float*)d_in[10];
  const float* b1     = (const float*)d_in[11];
  const float* g2     = (const float*)d_in[12];
  const float* b2     = (const float*)d_in[13];

  const int N = in_sizes[0] / D;
  const int E = in_sizes[2];
  float* out = (float*)d_out;

  // ws: dense_h f16[N*D] | s1[N] | s2[N] | row_ptr[N+1] | wt f16
  char* ws = (char*)d_ws;
  f16*   dense_h = (f16*)ws;
  float* s1      = (float*)(ws + (size_t)N * D * sizeof(f16));
  float* s2      = s1 + N;
  int*   row_ptr = (int*)(s2 + N);
  uintptr_t wtp  = (uintptr_t)(row_ptr + N + 1);
  wtp = (wtp + 15) & ~(uintptr_t)15;
  f16* wt = (f16*)wtp;

  prep_kernel<<<(E + 255) / 256, 256, 0, stream>>>(Ww, W1w, W2w, wt,
                                                   erow, row_ptr, E, N);
  node_kernel<<<512, 256, 0, stream>>>(query, input_, wt, Wb, W1b,
                                       W2b, g1, b1, dense_h, s1, s2, N);
  const int npairs = (N + 1) / 2;
  edge_kernel<<<2048, 256, 0, stream>>>(row_ptr, ecol, s1, s2,
                                        dense_h, g2, b2, out, N, npairs);
}